// Round 15
// baseline (2406.134 us; speedup 1.0000x reference)
//
#include <hip/hip_runtime.h>

#define NN 50000
#define NE 800000
#define TE (NE + NN)
#define FBLK 1563   // fused-kernel blocks: 16 waves each -> 25008 wave slots

__device__ __forceinline__ float lrelu02(float x) { return x >= 0.f ? x : 0.2f * x; }

typedef const __attribute__((address_space(1))) unsigned int* gas_ptr;
typedef __attribute__((address_space(3))) unsigned int* las_ptr;

__device__ __forceinline__ void dma16(const float* g, float* l) {
    __builtin_amdgcn_global_load_lds((gas_ptr)g, (las_ptr)l, 16, 0, 0);
}

__global__ void k_count(const int* __restrict__ ei, int* __restrict__ counts) {
    int e = blockIdx.x * blockDim.x + threadIdx.x;
    if (e >= TE) return;
    int dst = (e < NE) ? ei[NE + e] : (e - NE);
    atomicAdd(&counts[dst], 1);
}

__global__ void k_bsum(const int* __restrict__ counts, int* __restrict__ bsums) {
    __shared__ int sm[1024];
    int i = blockIdx.x * 1024 + threadIdx.x;
    sm[threadIdx.x] = (i < NN) ? counts[i] : 0;
    __syncthreads();
    for (int off = 512; off > 0; off >>= 1) {
        if ((int)threadIdx.x < off) sm[threadIdx.x] += sm[threadIdx.x + off];
        __syncthreads();
    }
    if (threadIdx.x == 0) bsums[blockIdx.x] = sm[0];
}

__global__ void k_bscan(const int* __restrict__ bsums, int* __restrict__ bex, int nb) {
    int l = threadIdx.x;
    int v = (l < nb) ? bsums[l] : 0;
    int orig = v;
    for (int d = 1; d < 64; d <<= 1) {
        int t = __shfl_up(v, d);
        if (l >= d) v += t;
    }
    if (l <= nb) bex[l] = v - orig;
}

__global__ void k_scan(const int* __restrict__ counts, const int* __restrict__ bex,
                       int* __restrict__ rowptr, int* __restrict__ cursor) {
    __shared__ int sm[1024];
    int t = threadIdx.x;
    int i = blockIdx.x * 1024 + t;
    int c = (i < NN) ? counts[i] : 0;
    sm[t] = c;
    __syncthreads();
    for (int off = 1; off < 1024; off <<= 1) {
        int v = (t >= off) ? sm[t - off] : 0;
        __syncthreads();
        sm[t] += v;
        __syncthreads();
    }
    int ex = bex[blockIdx.x] + sm[t] - c;
    if (i <= NN) rowptr[i] = ex;
    if (i < NN) cursor[i] = ex;
}

__global__ void k_scatter(const int* __restrict__ ei, int* __restrict__ cursor, int* __restrict__ csr) {
    int e = blockIdx.x * blockDim.x + threadIdx.x;
    if (e >= TE) return;
    int src, dst;
    if (e < NE) { src = ei[e]; dst = ei[NE + e]; }
    else { src = e - NE; dst = src; }
    int pos = atomicAdd(&cursor[dst], 1);
    csr[pos] = src;
}

// GEMM X[N,128] @ W[128,128] -> XS[N,128] + AL logits (layer 1 only).
// Round-13 structure: X staged via async global_load_lds burst, one barrier,
// compute from LDS + W from L2.
__global__ __launch_bounds__(256) void k_gemm(const float* __restrict__ X, const float* __restrict__ W,
                                              const float* __restrict__ as_, const float* __restrict__ ad_,
                                              float* __restrict__ XS, float* __restrict__ AL) {
    __shared__ float sX[64 * 128];   // 32 KB
    int t = threadIdx.x;
    int lane = t & 63;
    int wv = __builtin_amdgcn_readfirstlane(t >> 6);
    int tc = t & 31;
    int tr = t >> 5;
    size_t chunk = (size_t)blockIdx.x * 64;
    size_t base = chunk * 128;
    const size_t gmax = (size_t)NN * 128 - 4;
#pragma unroll
    for (int i = 0; i < 8; i++) {
        size_t off = ((size_t)(wv * 8 + i)) * 256 + (size_t)lane * 4;
        size_t g = base + off;
        if (g > gmax) g = gmax;
        dma16(X + g, &sX[off]);
    }
    __syncthreads();
    float4 av = *(const float4*)(as_ + tc * 4);
    float4 dv = *(const float4*)(ad_ + tc * 4);
    float acc[8][4];
#pragma unroll
    for (int i = 0; i < 8; i++)
#pragma unroll
        for (int j = 0; j < 4; j++) acc[i][j] = 0.f;
#pragma unroll 2
    for (int kk = 0; kk < 128; kk += 4) {
        float4 wq[4];
#pragma unroll
        for (int k = 0; k < 4; k++)
            wq[k] = *(const float4*)(W + (size_t)(kk + k) * 128 + tc * 4);
#pragma unroll
        for (int i = 0; i < 8; i++) {
            float4 xv = *(const float4*)(&sX[(tr * 8 + i) * 128 + kk]);
            acc[i][0] = fmaf(xv.x, wq[0].x, acc[i][0]);
            acc[i][1] = fmaf(xv.x, wq[0].y, acc[i][1]);
            acc[i][2] = fmaf(xv.x, wq[0].z, acc[i][2]);
            acc[i][3] = fmaf(xv.x, wq[0].w, acc[i][3]);
            acc[i][0] = fmaf(xv.y, wq[1].x, acc[i][0]);
            acc[i][1] = fmaf(xv.y, wq[1].y, acc[i][1]);
            acc[i][2] = fmaf(xv.y, wq[1].z, acc[i][2]);
            acc[i][3] = fmaf(xv.y, wq[1].w, acc[i][3]);
            acc[i][0] = fmaf(xv.z, wq[2].x, acc[i][0]);
            acc[i][1] = fmaf(xv.z, wq[2].y, acc[i][1]);
            acc[i][2] = fmaf(xv.z, wq[2].z, acc[i][2]);
            acc[i][3] = fmaf(xv.z, wq[2].w, acc[i][3]);
            acc[i][0] = fmaf(xv.w, wq[3].x, acc[i][0]);
            acc[i][1] = fmaf(xv.w, wq[3].y, acc[i][1]);
            acc[i][2] = fmaf(xv.w, wq[3].z, acc[i][2]);
            acc[i][3] = fmaf(xv.w, wq[3].w, acc[i][3]);
        }
    }
#pragma unroll
    for (int i = 0; i < 8; i++) {
        size_t row = chunk + tr * 8 + i;
        bool ok = row < NN;
        if (ok) {
            float4 o; o.x = acc[i][0]; o.y = acc[i][1]; o.z = acc[i][2]; o.w = acc[i][3];
            *(float4*)(XS + row * 128 + tc * 4) = o;
        }
        float s = acc[i][0] * av.x + acc[i][1] * av.y + acc[i][2] * av.z + acc[i][3] * av.w;
        float dd = acc[i][0] * dv.x + acc[i][1] * dv.y + acc[i][2] * dv.z + acc[i][3] * dv.w;
#pragma unroll
        for (int off = 8; off > 0; off >>= 1) {
            s += __shfl_xor(s, off);
            dd += __shfl_xor(dd, off);
        }
        if (ok && (tc & 15) == 0) {
            int h = tc >> 4;
            AL[row * 4 + h] = s;
            AL[row * 4 + 2 + h] = dd;
        }
    }
}

// Fused aggregation + next-layer GEMM row, block-level W staging.
// 16 waves/block; W (64 KB) staged once via DMA, one barrier, then each wave
// grid-strides over nodes INDEPENDENTLY: proven gather loop -> h in regs ->
// out cols (2l,2l+1) via batched ds_read_b64 of W rows + readlane broadcasts.
__global__ __launch_bounds__(1024) void k_agg_fused(const float* __restrict__ XS, const float* __restrict__ AL,
                                                    const int* __restrict__ rowptr, const int* __restrict__ csr,
                                                    const float* __restrict__ bias, const float* __restrict__ Wn,
                                                    const float* __restrict__ asn, const float* __restrict__ adn,
                                                    const float* __restrict__ prelu_a,
                                                    float* __restrict__ XS_out, float* __restrict__ AL_out) {
    __shared__ float sW[128 * 128];   // 64 KB
    int t = threadIdx.x;
    int lane = t & 63;
    int wv = t >> 6;
    // stage W: 1024 threads x 4 x 16B DMA (wave-contiguous LDS dest)
#pragma unroll
    for (int i = 0; i < 4; i++) {
        size_t off = ((size_t)(i * 1024 + t)) * 4;
        dma16(Wn + off, &sW[off]);
    }
    __syncthreads();

    float pa = prelu_a[0];
    int c = 2 * lane;
    float2 bv = *(const float2*)(bias + c);
    float2 a2 = *(const float2*)(asn + c);
    float2 d2 = *(const float2*)(adn + c);

    for (int n = blockIdx.x * 16 + wv; n < NN; n += FBLK * 16) {
        int beg = rowptr[n], end = rowptr[n + 1];
        float2 aldv = *(const float2*)(AL + (size_t)n * 4 + 2);
        float ald0 = aldv.x, ald1 = aldv.y;
        float acc_lo = 0.f, acc_hi = 0.f, den0 = 0.f, den1 = 0.f;
        for (int base = beg; base < end; base += 64) {
            int i = base + lane;
            float w0 = 0.f, w1 = 0.f;
            int sv = 0;
            if (i < end) {
                sv = csr[i];
                float2 av = *(const float2*)(AL + (size_t)sv * 4);
                w0 = __expf(lrelu02(av.x + ald0));
                w1 = __expf(lrelu02(av.y + ald1));
            }
            den0 += w0;
            den1 += w1;
            int cnt = min(64, end - base);
            int j = 0;
            for (; j + 8 <= cnt; j += 8) {
                int s[8];
                float ww[8];
#pragma unroll
                for (int jj = 0; jj < 8; jj++) {
                    s[jj] = __shfl(sv, j + jj);
                    float q0 = __shfl(w0, j + jj), q1 = __shfl(w1, j + jj);
                    ww[jj] = (lane < 32) ? q0 : q1;
                }
                float2 xv[8];
#pragma unroll
                for (int jj = 0; jj < 8; jj++)
                    xv[jj] = *(const float2*)(XS + (size_t)s[jj] * 128 + 2 * lane);
#pragma unroll
                for (int jj = 0; jj < 8; jj++) {
                    acc_lo = fmaf(ww[jj], xv[jj].x, acc_lo);
                    acc_hi = fmaf(ww[jj], xv[jj].y, acc_hi);
                }
            }
            for (; j < cnt; j++) {
                int s = __shfl(sv, j);
                float q0 = __shfl(w0, j), q1 = __shfl(w1, j);
                float w = (lane < 32) ? q0 : q1;
                float2 xv = *(const float2*)(XS + (size_t)s * 128 + 2 * lane);
                acc_lo = fmaf(w, xv.x, acc_lo);
                acc_hi = fmaf(w, xv.y, acc_hi);
            }
        }
#pragma unroll
        for (int off = 32; off > 0; off >>= 1) {
            den0 += __shfl_xor(den0, off);
            den1 += __shfl_xor(den1, off);
        }
        float densel = (lane < 32) ? den0 : den1;
        float inv = 1.f / (densel + 1e-16f);
        float v0 = acc_lo * inv + bv.x;
        float v1 = acc_hi * inv + bv.y;
        v0 = v0 >= 0.f ? v0 : pa * v0;   // h[2*lane]
        v1 = v1 >= 0.f ? v1 : pa * v1;   // h[2*lane+1]
        // ---- fused gemm row from LDS W: out[c] = sum_k h[k]*W[k][c] ----
        float o0 = 0.f, o1 = 0.f;
#pragma unroll
        for (int kb = 0; kb < 16; kb++) {
            float2 wq[8];
#pragma unroll
            for (int j = 0; j < 8; j++)
                wq[j] = *(const float2*)(&sW[(kb * 8 + j) * 128 + c]);
#pragma unroll
            for (int j = 0; j < 8; j++) {
                int k = kb * 8 + j;
                float hk = __shfl((k & 1) ? v1 : v0, k >> 1);   // uniform -> readlane
                o0 = fmaf(hk, wq[j].x, o0);
                o1 = fmaf(hk, wq[j].y, o1);
            }
        }
        float2 ov; ov.x = o0; ov.y = o1;
        *(float2*)(XS_out + (size_t)n * 128 + c) = ov;
        float s = o0 * a2.x + o1 * a2.y;
        float dd = o0 * d2.x + o1 * d2.y;
#pragma unroll
        for (int off = 16; off > 0; off >>= 1) {
            s += __shfl_xor(s, off);
            dd += __shfl_xor(dd, off);
        }
        if (lane == 0) {
            AL_out[(size_t)n * 4 + 0] = s;
            AL_out[(size_t)n * 4 + 2] = dd;
        }
        if (lane == 32) {
            AL_out[(size_t)n * 4 + 1] = s;
            AL_out[(size_t)n * 4 + 3] = dd;
        }
    }
}

// Last-layer aggregation (round-4/7 structure EXACT): mean heads, +b3, prelu,
// dot lp_w -> out[N].
__global__ __launch_bounds__(256) void k_agg_last(const float* __restrict__ XS, const float* __restrict__ AL,
                                                  const int* __restrict__ rowptr, const int* __restrict__ csr,
                                                  const float* __restrict__ bias, const float* __restrict__ lp_w,
                                                  const float* __restrict__ lp_b, const float* __restrict__ prelu_a,
                                                  float* __restrict__ out) {
    int wv = threadIdx.x >> 6, lane = threadIdx.x & 63;
    int n = blockIdx.x * 4 + wv;
    if (n >= NN) return;
    int beg = rowptr[n], end = rowptr[n + 1];
    float2 aldv = *(const float2*)(AL + (size_t)n * 4 + 2);
    float ald0 = aldv.x, ald1 = aldv.y;
    float acc_lo = 0.f, acc_hi = 0.f, den0 = 0.f, den1 = 0.f;
    for (int base = beg; base < end; base += 64) {
        int i = base + lane;
        float w0 = 0.f, w1 = 0.f;
        int sv = 0;
        if (i < end) {
            sv = csr[i];
            float2 av = *(const float2*)(AL + (size_t)sv * 4);
            w0 = __expf(lrelu02(av.x + ald0));
            w1 = __expf(lrelu02(av.y + ald1));
        }
        den0 += w0;
        den1 += w1;
        int cnt = min(64, end - base);
        int j = 0;
        for (; j + 8 <= cnt; j += 8) {
            int s[8];
            float ww[8];
#pragma unroll
            for (int jj = 0; jj < 8; jj++) {
                s[jj] = __shfl(sv, j + jj);
                float q0 = __shfl(w0, j + jj), q1 = __shfl(w1, j + jj);
                ww[jj] = (lane < 32) ? q0 : q1;
            }
            float2 xv[8];
#pragma unroll
            for (int jj = 0; jj < 8; jj++)
                xv[jj] = *(const float2*)(XS + (size_t)s[jj] * 128 + 2 * lane);
#pragma unroll
            for (int jj = 0; jj < 8; jj++) {
                acc_lo = fmaf(ww[jj], xv[jj].x, acc_lo);
                acc_hi = fmaf(ww[jj], xv[jj].y, acc_hi);
            }
        }
        for (; j < cnt; j++) {
            int s = __shfl(sv, j);
            float q0 = __shfl(w0, j), q1 = __shfl(w1, j);
            float w = (lane < 32) ? q0 : q1;
            float2 xv = *(const float2*)(XS + (size_t)s * 128 + 2 * lane);
            acc_lo = fmaf(w, xv.x, acc_lo);
            acc_hi = fmaf(w, xv.y, acc_hi);
        }
    }
#pragma unroll
    for (int off = 32; off > 0; off >>= 1) {
        den0 += __shfl_xor(den0, off);
        den1 += __shfl_xor(den1, off);
    }
    float pa = prelu_a[0];
    float densel = (lane < 32) ? den0 : den1;
    float inv = 1.f / (densel + 1e-16f);
    float hlo = acc_lo * inv, hhi = acc_hi * inv;
    float olo = __shfl_xor(hlo, 32), ohi = __shfl_xor(hhi, 32);
    float p = 0.f;
    if (lane < 32) {
        int c = 2 * lane;
        float v0 = 0.5f * (hlo + olo) + bias[c];
        float v1 = 0.5f * (hhi + ohi) + bias[c + 1];
        v0 = v0 >= 0.f ? v0 : pa * v0;
        v1 = v1 >= 0.f ? v1 : pa * v1;
        p = v0 * lp_w[c] + v1 * lp_w[c + 1];
    }
#pragma unroll
    for (int off = 32; off > 0; off >>= 1) p += __shfl_xor(p, off);
    if (lane == 0) out[n] = p + lp_b[0];
}

extern "C" void kernel_launch(void* const* d_in, const int* in_sizes, int n_in,
                              void* d_out, int out_size, void* d_ws, size_t ws_size,
                              hipStream_t stream) {
    const float* x   = (const float*)d_in[0];
    const int*   ei  = (const int*)d_in[1];
    const float* W1  = (const float*)d_in[2];
    const float* as1 = (const float*)d_in[3];
    const float* ad1 = (const float*)d_in[4];
    const float* b1  = (const float*)d_in[5];
    const float* W2  = (const float*)d_in[6];
    const float* as2 = (const float*)d_in[7];
    const float* ad2 = (const float*)d_in[8];
    const float* b2  = (const float*)d_in[9];
    const float* W3  = (const float*)d_in[10];
    const float* as3 = (const float*)d_in[11];
    const float* ad3 = (const float*)d_in[12];
    const float* b3  = (const float*)d_in[13];
    const float* lpw = (const float*)d_in[14];
    const float* lpb = (const float*)d_in[15];
    const float* pa  = (const float*)d_in[16];
    float* out = (float*)d_out;

    char* ws = (char*)d_ws;
    size_t off = 0;
    auto alloc = [&](size_t bytes) {
        void* p = ws + off;
        off = (off + bytes + 255) & ~(size_t)255;
        return p;
    };
    int*   rowptr = (int*)alloc((NN + 1) * sizeof(int));
    int*   cursor = (int*)alloc((NN + 1) * sizeof(int));
    int*   counts = (int*)alloc((size_t)NN * sizeof(int));
    int*   bsums  = (int*)alloc(64 * sizeof(int));
    int*   bex    = (int*)alloc(64 * sizeof(int));
    int*   csr    = (int*)alloc((size_t)TE * sizeof(int));
    float* al     = (float*)alloc((size_t)NN * 4 * sizeof(float));
    float* al2    = (float*)alloc((size_t)NN * 4 * sizeof(float));
    float* xs     = (float*)alloc((size_t)NN * 128 * sizeof(float));
    float* h      = (float*)alloc((size_t)NN * 128 * sizeof(float));
    (void)ws_size; (void)n_in; (void)in_sizes; (void)out_size;

    const int NB = (NN + 1023) / 1024;       // 49
    const int GEMM_GRID = (NN + 63) / 64;    // 782
    const int AGG_GRID  = (NN + 3) / 4;      // 12500

    hipMemsetAsync(counts, 0, (size_t)NN * sizeof(int), stream);
    k_count<<<(TE + 255) / 256, 256, 0, stream>>>(ei, counts);
    k_bsum<<<NB, 1024, 0, stream>>>(counts, bsums);
    k_bscan<<<1, 64, 0, stream>>>(bsums, bex, NB);
    k_scan<<<NB, 1024, 0, stream>>>(counts, bex, rowptr, cursor);
    k_scatter<<<(TE + 255) / 256, 256, 0, stream>>>(ei, cursor, csr);

    k_gemm<<<GEMM_GRID, 256, 0, stream>>>(x, W1, as1, ad1, xs, al);
    // layer1 agg + layer2 gemm fused (W2 in LDS): reads xs/al -> writes h/al2
    k_agg_fused<<<FBLK, 1024, 0, stream>>>(xs, al, rowptr, csr, b1, W2, as2, ad2, pa, h, al2);
    // layer2 agg + layer3 gemm fused (W3 in LDS): reads h/al2 -> writes xs/al
    k_agg_fused<<<FBLK, 1024, 0, stream>>>(h, al2, rowptr, csr, b2, W3, as3, ad3, pa, xs, al);
    // layer3 agg + head-mean + level predictor
    k_agg_last<<<AGG_GRID, 256, 0, stream>>>(xs, al, rowptr, csr, b3, lpw, lpb, pa, out);
}

// Round 16
// 399.303 us; speedup vs baseline: 6.0258x; 6.0258x over previous
//
#include <hip/hip_runtime.h>

#define NN 50000
#define NE 800000
#define TE (NE + NN)
#define CHUNK 32

__device__ __forceinline__ float lrelu02(float x) { return x >= 0.f ? x : 0.2f * x; }

typedef const __attribute__((address_space(1))) unsigned int* gas_ptr;
typedef __attribute__((address_space(3))) unsigned int* las_ptr;

__device__ __forceinline__ void dma16(const float* g, float* l) {
    __builtin_amdgcn_global_load_lds((gas_ptr)g, (las_ptr)l, 16, 0, 0);
}

__global__ void k_count(const int* __restrict__ ei, int* __restrict__ counts) {
    int e = blockIdx.x * blockDim.x + threadIdx.x;
    if (e >= TE) return;
    int dst = (e < NE) ? ei[NE + e] : (e - NE);
    atomicAdd(&counts[dst], 1);
}

__global__ void k_bsum(const int* __restrict__ counts, int* __restrict__ bsums) {
    __shared__ int sm[1024];
    int i = blockIdx.x * 1024 + threadIdx.x;
    sm[threadIdx.x] = (i < NN) ? counts[i] : 0;
    __syncthreads();
    for (int off = 512; off > 0; off >>= 1) {
        if ((int)threadIdx.x < off) sm[threadIdx.x] += sm[threadIdx.x + off];
        __syncthreads();
    }
    if (threadIdx.x == 0) bsums[blockIdx.x] = sm[0];
}

__global__ void k_bscan(const int* __restrict__ bsums, int* __restrict__ bex, int nb) {
    int l = threadIdx.x;
    int v = (l < nb) ? bsums[l] : 0;
    int orig = v;
    for (int d = 1; d < 64; d <<= 1) {
        int t = __shfl_up(v, d);
        if (l >= d) v += t;
    }
    if (l <= nb) bex[l] = v - orig;
}

__global__ void k_scan(const int* __restrict__ counts, const int* __restrict__ bex,
                       int* __restrict__ rowptr, int* __restrict__ cursor) {
    __shared__ int sm[1024];
    int t = threadIdx.x;
    int i = blockIdx.x * 1024 + t;
    int c = (i < NN) ? counts[i] : 0;
    sm[t] = c;
    __syncthreads();
    for (int off = 1; off < 1024; off <<= 1) {
        int v = (t >= off) ? sm[t - off] : 0;
        __syncthreads();
        sm[t] += v;
        __syncthreads();
    }
    int ex = bex[blockIdx.x] + sm[t] - c;
    if (i <= NN) rowptr[i] = ex;
    if (i < NN) cursor[i] = ex;
}

__global__ void k_scatter(const int* __restrict__ ei, int* __restrict__ cursor, int* __restrict__ csr) {
    int e = blockIdx.x * blockDim.x + threadIdx.x;
    if (e >= TE) return;
    int src, dst;
    if (e < NE) { src = ei[e]; dst = ei[NE + e]; }
    else { src = e - NE; dst = src; }
    int pos = atomicAdd(&cursor[dst], 1);
    csr[pos] = src;
}

// GEMM X[N,128] @ W[128,128] -> XS[N,128] + AL logits.
// 256-thr block owns a 32-row chunk (16 KB LDS -> up to 8 resident blocks/CU:
// inter-block overlap hides the DMA stage, the only mechanism that survives
// the compiler's vmcnt(0)-before-barrier drain). 4 rows x 4 cols per thread;
// X from LDS (half-wave broadcast), W from L2.
__global__ __launch_bounds__(256) void k_gemm(const float* __restrict__ X, const float* __restrict__ W,
                                              const float* __restrict__ as_, const float* __restrict__ ad_,
                                              float* __restrict__ XS, float* __restrict__ AL) {
    __shared__ float sX[CHUNK * 128];   // 16 KB
    int t = threadIdx.x;
    int tc = t & 31;     // col quad: cols 4*tc .. 4*tc+3
    int tr = t >> 5;     // row quad: rows tr*4 .. tr*4+3 within chunk
    size_t chunk = (size_t)blockIdx.x * CHUNK;
    size_t base = chunk * 128;
    const size_t gmax = (size_t)NN * 128 - 4;
    // ---- burst stage: 4096 floats = 1024 float4, 4 per thread ----
#pragma unroll
    for (int i = 0; i < 4; i++) {
        size_t off = ((size_t)(i * 256 + t)) * 4;
        size_t g = base + off;
        if (g > gmax) g = gmax;        // clamp (dup reads; stores guarded)
        dma16(X + g, &sX[off]);
    }
    __syncthreads();
    float4 av = *(const float4*)(as_ + tc * 4);
    float4 dv = *(const float4*)(ad_ + tc * 4);
    float acc[4][4];
#pragma unroll
    for (int i = 0; i < 4; i++)
#pragma unroll
        for (int j = 0; j < 4; j++) acc[i][j] = 0.f;
#pragma unroll 2
    for (int kk = 0; kk < 128; kk += 4) {
        float4 wq[4];
#pragma unroll
        for (int k = 0; k < 4; k++)
            wq[k] = *(const float4*)(W + (size_t)(kk + k) * 128 + tc * 4);
#pragma unroll
        for (int i = 0; i < 4; i++) {
            float4 xv = *(const float4*)(&sX[(tr * 4 + i) * 128 + kk]);  // half-wave broadcast
            acc[i][0] = fmaf(xv.x, wq[0].x, acc[i][0]);
            acc[i][1] = fmaf(xv.x, wq[0].y, acc[i][1]);
            acc[i][2] = fmaf(xv.x, wq[0].z, acc[i][2]);
            acc[i][3] = fmaf(xv.x, wq[0].w, acc[i][3]);
            acc[i][0] = fmaf(xv.y, wq[1].x, acc[i][0]);
            acc[i][1] = fmaf(xv.y, wq[1].y, acc[i][1]);
            acc[i][2] = fmaf(xv.y, wq[1].z, acc[i][2]);
            acc[i][3] = fmaf(xv.y, wq[1].w, acc[i][3]);
            acc[i][0] = fmaf(xv.z, wq[2].x, acc[i][0]);
            acc[i][1] = fmaf(xv.z, wq[2].y, acc[i][1]);
            acc[i][2] = fmaf(xv.z, wq[2].z, acc[i][2]);
            acc[i][3] = fmaf(xv.z, wq[2].w, acc[i][3]);
            acc[i][0] = fmaf(xv.w, wq[3].x, acc[i][0]);
            acc[i][1] = fmaf(xv.w, wq[3].y, acc[i][1]);
            acc[i][2] = fmaf(xv.w, wq[3].z, acc[i][2]);
            acc[i][3] = fmaf(xv.w, wq[3].w, acc[i][3]);
        }
    }
#pragma unroll
    for (int i = 0; i < 4; i++) {
        size_t row = chunk + tr * 4 + i;
        bool ok = row < NN;
        if (ok) {
            float4 o; o.x = acc[i][0]; o.y = acc[i][1]; o.z = acc[i][2]; o.w = acc[i][3];
            *(float4*)(XS + row * 128 + tc * 4) = o;
        }
        float s = acc[i][0] * av.x + acc[i][1] * av.y + acc[i][2] * av.z + acc[i][3] * av.w;
        float dd = acc[i][0] * dv.x + acc[i][1] * dv.y + acc[i][2] * dv.z + acc[i][3] * dv.w;
#pragma unroll
        for (int off = 8; off > 0; off >>= 1) {
            s += __shfl_xor(s, off);
            dd += __shfl_xor(dd, off);
        }
        if (ok && (tc & 15) == 0) {
            int h = tc >> 4;
            AL[row * 4 + h] = s;
            AL[row * 4 + 2 + h] = dd;
        }
    }
}

// Aggregation: round-4/7 structure EXACT (proven 64.5us, fabric-bound at the
// compulsory per-XCD fill floor ~206MB @ ~3.67 TB/s).
template <int LAST>
__global__ __launch_bounds__(256) void k_agg(const float* __restrict__ XS, const float* __restrict__ AL,
                                             const int* __restrict__ rowptr, const int* __restrict__ csr,
                                             const float* __restrict__ bias, const float* __restrict__ lp_w,
                                             const float* __restrict__ lp_b, const float* __restrict__ prelu_a,
                                             float* __restrict__ out) {
    int wv = threadIdx.x >> 6, lane = threadIdx.x & 63;
    int n = blockIdx.x * 4 + wv;
    if (n >= NN) return;
    int beg = rowptr[n], end = rowptr[n + 1];
    float2 aldv = *(const float2*)(AL + (size_t)n * 4 + 2);
    float ald0 = aldv.x, ald1 = aldv.y;
    float acc_lo = 0.f, acc_hi = 0.f, den0 = 0.f, den1 = 0.f;
    for (int base = beg; base < end; base += 64) {
        int i = base + lane;
        float w0 = 0.f, w1 = 0.f;
        int sv = 0;
        if (i < end) {
            sv = csr[i];
            float2 av = *(const float2*)(AL + (size_t)sv * 4);
            w0 = __expf(lrelu02(av.x + ald0));
            w1 = __expf(lrelu02(av.y + ald1));
        }
        den0 += w0;
        den1 += w1;
        int cnt = min(64, end - base);
        int j = 0;
        for (; j + 8 <= cnt; j += 8) {
            int s[8];
            float ww[8];
#pragma unroll
            for (int jj = 0; jj < 8; jj++) {
                s[jj] = __shfl(sv, j + jj);
                float q0 = __shfl(w0, j + jj), q1 = __shfl(w1, j + jj);
                ww[jj] = (lane < 32) ? q0 : q1;
            }
            float2 xv[8];
#pragma unroll
            for (int jj = 0; jj < 8; jj++)
                xv[jj] = *(const float2*)(XS + (size_t)s[jj] * 128 + 2 * lane);
#pragma unroll
            for (int jj = 0; jj < 8; jj++) {
                acc_lo = fmaf(ww[jj], xv[jj].x, acc_lo);
                acc_hi = fmaf(ww[jj], xv[jj].y, acc_hi);
            }
        }
        for (; j < cnt; j++) {
            int s = __shfl(sv, j);
            float q0 = __shfl(w0, j), q1 = __shfl(w1, j);
            float w = (lane < 32) ? q0 : q1;
            float2 xv = *(const float2*)(XS + (size_t)s * 128 + 2 * lane);
            acc_lo = fmaf(w, xv.x, acc_lo);
            acc_hi = fmaf(w, xv.y, acc_hi);
        }
    }
#pragma unroll
    for (int off = 32; off > 0; off >>= 1) {
        den0 += __shfl_xor(den0, off);
        den1 += __shfl_xor(den1, off);
    }
    float pa = prelu_a[0];
    float densel = (lane < 32) ? den0 : den1;
    float inv = 1.f / (densel + 1e-16f);
    if (LAST) {
        float hlo = acc_lo * inv, hhi = acc_hi * inv;
        float olo = __shfl_xor(hlo, 32), ohi = __shfl_xor(hhi, 32);
        float p = 0.f;
        if (lane < 32) {
            int c = 2 * lane;
            float v0 = 0.5f * (hlo + olo) + bias[c];
            float v1 = 0.5f * (hhi + ohi) + bias[c + 1];
            v0 = v0 >= 0.f ? v0 : pa * v0;
            v1 = v1 >= 0.f ? v1 : pa * v1;
            p = v0 * lp_w[c] + v1 * lp_w[c + 1];
        }
#pragma unroll
        for (int off = 32; off > 0; off >>= 1) p += __shfl_xor(p, off);
        if (lane == 0) out[n] = p + lp_b[0];
    } else {
        int c = 2 * lane;
        float2 bv = *(const float2*)(bias + c);
        float v0 = acc_lo * inv + bv.x;
        float v1 = acc_hi * inv + bv.y;
        v0 = v0 >= 0.f ? v0 : pa * v0;
        v1 = v1 >= 0.f ? v1 : pa * v1;
        float2 o; o.x = v0; o.y = v1;
        *(float2*)(out + (size_t)n * 128 + c) = o;
    }
}

extern "C" void kernel_launch(void* const* d_in, const int* in_sizes, int n_in,
                              void* d_out, int out_size, void* d_ws, size_t ws_size,
                              hipStream_t stream) {
    const float* x   = (const float*)d_in[0];
    const int*   ei  = (const int*)d_in[1];
    const float* W1  = (const float*)d_in[2];
    const float* as1 = (const float*)d_in[3];
    const float* ad1 = (const float*)d_in[4];
    const float* b1  = (const float*)d_in[5];
    const float* W2  = (const float*)d_in[6];
    const float* as2 = (const float*)d_in[7];
    const float* ad2 = (const float*)d_in[8];
    const float* b2  = (const float*)d_in[9];
    const float* W3  = (const float*)d_in[10];
    const float* as3 = (const float*)d_in[11];
    const float* ad3 = (const float*)d_in[12];
    const float* b3  = (const float*)d_in[13];
    const float* lpw = (const float*)d_in[14];
    const float* lpb = (const float*)d_in[15];
    const float* pa  = (const float*)d_in[16];
    float* out = (float*)d_out;

    char* ws = (char*)d_ws;
    size_t off = 0;
    auto alloc = [&](size_t bytes) {
        void* p = ws + off;
        off = (off + bytes + 255) & ~(size_t)255;
        return p;
    };
    int*   rowptr = (int*)alloc((NN + 1) * sizeof(int));
    int*   cursor = (int*)alloc((NN + 1) * sizeof(int));
    int*   counts = (int*)alloc((size_t)NN * sizeof(int));
    int*   bsums  = (int*)alloc(64 * sizeof(int));
    int*   bex    = (int*)alloc(64 * sizeof(int));
    int*   csr    = (int*)alloc((size_t)TE * sizeof(int));
    float* al     = (float*)alloc((size_t)NN * 4 * sizeof(float));
    float* xs     = (float*)alloc((size_t)NN * 128 * sizeof(float));
    float* h      = (float*)alloc((size_t)NN * 128 * sizeof(float));
    (void)ws_size; (void)n_in; (void)in_sizes; (void)out_size;

    const int NB = (NN + 1023) / 1024;           // 49
    const int GEMM_GRID = (NN + CHUNK - 1) / CHUNK;  // 1563
    const int AGG_GRID  = (NN + 3) / 4;          // 12500

    hipMemsetAsync(counts, 0, (size_t)NN * sizeof(int), stream);
    k_count<<<(TE + 255) / 256, 256, 0, stream>>>(ei, counts);
    k_bsum<<<NB, 1024, 0, stream>>>(counts, bsums);
    k_bscan<<<1, 64, 0, stream>>>(bsums, bex, NB);
    k_scan<<<NB, 1024, 0, stream>>>(counts, bex, rowptr, cursor);
    k_scatter<<<(TE + 255) / 256, 256, 0, stream>>>(ei, cursor, csr);

    k_gemm<<<GEMM_GRID, 256, 0, stream>>>(x, W1, as1, ad1, xs, al);
    k_agg<0><<<AGG_GRID, 256, 0, stream>>>(xs, al, rowptr, csr, b1, nullptr, nullptr, pa, h);
    k_gemm<<<GEMM_GRID, 256, 0, stream>>>(h, W2, as2, ad2, xs, al);
    k_agg<0><<<AGG_GRID, 256, 0, stream>>>(xs, al, rowptr, csr, b2, nullptr, nullptr, pa, h);
    k_gemm<<<GEMM_GRID, 256, 0, stream>>>(h, W3, as3, ad3, xs, al);
    k_agg<1><<<AGG_GRID, 256, 0, stream>>>(xs, al, rowptr, csr, b3, lpw, lpb, pa, out);
}

// Round 18
// 385.351 us; speedup vs baseline: 6.2440x; 1.0362x over previous
//
#include <hip/hip_runtime.h>

#define NN 50000
#define NE 800000
#define TE (NE + NN)

__device__ __forceinline__ float lrelu02(float x) { return x >= 0.f ? x : 0.2f * x; }

typedef const __attribute__((address_space(1))) unsigned int* gas_ptr;
typedef __attribute__((address_space(3))) unsigned int* las_ptr;
typedef float vf4 __attribute__((ext_vector_type(4)));
typedef float vf2 __attribute__((ext_vector_type(2)));

__device__ __forceinline__ void dma16(const float* g, float* l) {
    __builtin_amdgcn_global_load_lds((gas_ptr)g, (las_ptr)l, 16, 0, 0);
}

__device__ __forceinline__ void nt_store4(float* p, float a, float b, float c, float d) {
    vf4 v; v.x = a; v.y = b; v.z = c; v.w = d;
    __builtin_nontemporal_store(v, (vf4*)p);
}

__device__ __forceinline__ void nt_store2(float* p, float a, float b) {
    vf2 v; v.x = a; v.y = b;
    __builtin_nontemporal_store(v, (vf2*)p);
}

__global__ void k_count(const int* __restrict__ ei, int* __restrict__ counts) {
    int e = blockIdx.x * blockDim.x + threadIdx.x;
    if (e >= TE) return;
    int dst = (e < NE) ? ei[NE + e] : (e - NE);
    atomicAdd(&counts[dst], 1);
}

__global__ void k_bsum(const int* __restrict__ counts, int* __restrict__ bsums) {
    __shared__ int sm[1024];
    int i = blockIdx.x * 1024 + threadIdx.x;
    sm[threadIdx.x] = (i < NN) ? counts[i] : 0;
    __syncthreads();
    for (int off = 512; off > 0; off >>= 1) {
        if ((int)threadIdx.x < off) sm[threadIdx.x] += sm[threadIdx.x + off];
        __syncthreads();
    }
    if (threadIdx.x == 0) bsums[blockIdx.x] = sm[0];
}

__global__ void k_bscan(const int* __restrict__ bsums, int* __restrict__ bex, int nb) {
    int l = threadIdx.x;
    int v = (l < nb) ? bsums[l] : 0;
    int orig = v;
    for (int d = 1; d < 64; d <<= 1) {
        int t = __shfl_up(v, d);
        if (l >= d) v += t;
    }
    if (l <= nb) bex[l] = v - orig;
}

__global__ void k_scan(const int* __restrict__ counts, const int* __restrict__ bex,
                       int* __restrict__ rowptr, int* __restrict__ cursor) {
    __shared__ int sm[1024];
    int t = threadIdx.x;
    int i = blockIdx.x * 1024 + t;
    int c = (i < NN) ? counts[i] : 0;
    sm[t] = c;
    __syncthreads();
    for (int off = 1; off < 1024; off <<= 1) {
        int v = (t >= off) ? sm[t - off] : 0;
        __syncthreads();
        sm[t] += v;
        __syncthreads();
    }
    int ex = bex[blockIdx.x] + sm[t] - c;
    if (i <= NN) rowptr[i] = ex;
    if (i < NN) cursor[i] = ex;
}

__global__ void k_scatter(const int* __restrict__ ei, int* __restrict__ cursor, int* __restrict__ csr) {
    int e = blockIdx.x * blockDim.x + threadIdx.x;
    if (e >= TE) return;
    int src, dst;
    if (e < NE) { src = ei[e]; dst = ei[NE + e]; }
    else { src = e - NE; dst = src; }
    int pos = atomicAdd(&cursor[dst], 1);
    csr[pos] = src;
}

// GEMM X[N,128] @ W[128,128] -> XS[N,128] + AL logits. Round-13 structure
// (best known) + NON-TEMPORAL XS stores (nt flag): stream writes past L2 so
// the next kernel doesn't start against a dirty-L2 writeback drain.
__global__ __launch_bounds__(256) void k_gemm(const float* __restrict__ X, const float* __restrict__ W,
                                              const float* __restrict__ as_, const float* __restrict__ ad_,
                                              float* __restrict__ XS, float* __restrict__ AL) {
    __shared__ float sX[64 * 128];   // 32 KB
    int t = threadIdx.x;
    int lane = t & 63;
    int wv = __builtin_amdgcn_readfirstlane(t >> 6);
    int tc = t & 31;
    int tr = t >> 5;
    size_t chunk = (size_t)blockIdx.x * 64;
    size_t base = chunk * 128;
    const size_t gmax = (size_t)NN * 128 - 4;
#pragma unroll
    for (int i = 0; i < 8; i++) {
        size_t off = ((size_t)(wv * 8 + i)) * 256 + (size_t)lane * 4;
        size_t g = base + off;
        if (g > gmax) g = gmax;
        dma16(X + g, &sX[off]);
    }
    __syncthreads();
    float4 av = *(const float4*)(as_ + tc * 4);
    float4 dv = *(const float4*)(ad_ + tc * 4);
    float acc[8][4];
#pragma unroll
    for (int i = 0; i < 8; i++)
#pragma unroll
        for (int j = 0; j < 4; j++) acc[i][j] = 0.f;
#pragma unroll 2
    for (int kk = 0; kk < 128; kk += 4) {
        float4 wq[4];
#pragma unroll
        for (int k = 0; k < 4; k++)
            wq[k] = *(const float4*)(W + (size_t)(kk + k) * 128 + tc * 4);
#pragma unroll
        for (int i = 0; i < 8; i++) {
            float4 xv = *(const float4*)(&sX[(tr * 8 + i) * 128 + kk]);
            acc[i][0] = fmaf(xv.x, wq[0].x, acc[i][0]);
            acc[i][1] = fmaf(xv.x, wq[0].y, acc[i][1]);
            acc[i][2] = fmaf(xv.x, wq[0].z, acc[i][2]);
            acc[i][3] = fmaf(xv.x, wq[0].w, acc[i][3]);
            acc[i][0] = fmaf(xv.y, wq[1].x, acc[i][0]);
            acc[i][1] = fmaf(xv.y, wq[1].y, acc[i][1]);
            acc[i][2] = fmaf(xv.y, wq[1].z, acc[i][2]);
            acc[i][3] = fmaf(xv.y, wq[1].w, acc[i][3]);
            acc[i][0] = fmaf(xv.z, wq[2].x, acc[i][0]);
            acc[i][1] = fmaf(xv.z, wq[2].y, acc[i][1]);
            acc[i][2] = fmaf(xv.z, wq[2].z, acc[i][2]);
            acc[i][3] = fmaf(xv.z, wq[2].w, acc[i][3]);
            acc[i][0] = fmaf(xv.w, wq[3].x, acc[i][0]);
            acc[i][1] = fmaf(xv.w, wq[3].y, acc[i][1]);
            acc[i][2] = fmaf(xv.w, wq[3].z, acc[i][2]);
            acc[i][3] = fmaf(xv.w, wq[3].w, acc[i][3]);
        }
    }
#pragma unroll
    for (int i = 0; i < 8; i++) {
        size_t row = chunk + tr * 8 + i;
        bool ok = row < NN;
        if (ok) {
            nt_store4(XS + row * 128 + tc * 4, acc[i][0], acc[i][1], acc[i][2], acc[i][3]);
        }
        float s = acc[i][0] * av.x + acc[i][1] * av.y + acc[i][2] * av.z + acc[i][3] * av.w;
        float dd = acc[i][0] * dv.x + acc[i][1] * dv.y + acc[i][2] * dv.z + acc[i][3] * dv.w;
#pragma unroll
        for (int off = 8; off > 0; off >>= 1) {
            s += __shfl_xor(s, off);
            dd += __shfl_xor(dd, off);
        }
        if (ok && (tc & 15) == 0) {
            int h = tc >> 4;
            AL[row * 4 + h] = s;
            AL[row * 4 + 2 + h] = dd;
        }
    }
}

// Aggregation: round-4/7 structure EXACT (fabric-bound, 206MB @ ~3.67 TB/s)
// + NON-TEMPORAL h stores (LAST=0) to avoid dirtying L2 for the next gemm.
template <int LAST>
__global__ __launch_bounds__(256) void k_agg(const float* __restrict__ XS, const float* __restrict__ AL,
                                             const int* __restrict__ rowptr, const int* __restrict__ csr,
                                             const float* __restrict__ bias, const float* __restrict__ lp_w,
                                             const float* __restrict__ lp_b, const float* __restrict__ prelu_a,
                                             float* __restrict__ out) {
    int wv = threadIdx.x >> 6, lane = threadIdx.x & 63;
    int n = blockIdx.x * 4 + wv;
    if (n >= NN) return;
    int beg = rowptr[n], end = rowptr[n + 1];
    float2 aldv = *(const float2*)(AL + (size_t)n * 4 + 2);
    float ald0 = aldv.x, ald1 = aldv.y;
    float acc_lo = 0.f, acc_hi = 0.f, den0 = 0.f, den1 = 0.f;
    for (int base = beg; base < end; base += 64) {
        int i = base + lane;
        float w0 = 0.f, w1 = 0.f;
        int sv = 0;
        if (i < end) {
            sv = csr[i];
            float2 av = *(const float2*)(AL + (size_t)sv * 4);
            w0 = __expf(lrelu02(av.x + ald0));
            w1 = __expf(lrelu02(av.y + ald1));
        }
        den0 += w0;
        den1 += w1;
        int cnt = min(64, end - base);
        int j = 0;
        for (; j + 8 <= cnt; j += 8) {
            int s[8];
            float ww[8];
#pragma unroll
            for (int jj = 0; jj < 8; jj++) {
                s[jj] = __shfl(sv, j + jj);
                float q0 = __shfl(w0, j + jj), q1 = __shfl(w1, j + jj);
                ww[jj] = (lane < 32) ? q0 : q1;
            }
            float2 xv[8];
#pragma unroll
            for (int jj = 0; jj < 8; jj++)
                xv[jj] = *(const float2*)(XS + (size_t)s[jj] * 128 + 2 * lane);
#pragma unroll
            for (int jj = 0; jj < 8; jj++) {
                acc_lo = fmaf(ww[jj], xv[jj].x, acc_lo);
                acc_hi = fmaf(ww[jj], xv[jj].y, acc_hi);
            }
        }
        for (; j < cnt; j++) {
            int s = __shfl(sv, j);
            float q0 = __shfl(w0, j), q1 = __shfl(w1, j);
            float w = (lane < 32) ? q0 : q1;
            float2 xv = *(const float2*)(XS + (size_t)s * 128 + 2 * lane);
            acc_lo = fmaf(w, xv.x, acc_lo);
            acc_hi = fmaf(w, xv.y, acc_hi);
        }
    }
#pragma unroll
    for (int off = 32; off > 0; off >>= 1) {
        den0 += __shfl_xor(den0, off);
        den1 += __shfl_xor(den1, off);
    }
    float pa = prelu_a[0];
    float densel = (lane < 32) ? den0 : den1;
    float inv = 1.f / (densel + 1e-16f);
    if (LAST) {
        float hlo = acc_lo * inv, hhi = acc_hi * inv;
        float olo = __shfl_xor(hlo, 32), ohi = __shfl_xor(hhi, 32);
        float p = 0.f;
        if (lane < 32) {
            int c = 2 * lane;
            float v0 = 0.5f * (hlo + olo) + bias[c];
            float v1 = 0.5f * (hhi + ohi) + bias[c + 1];
            v0 = v0 >= 0.f ? v0 : pa * v0;
            v1 = v1 >= 0.f ? v1 : pa * v1;
            p = v0 * lp_w[c] + v1 * lp_w[c + 1];
        }
#pragma unroll
        for (int off = 32; off > 0; off >>= 1) p += __shfl_xor(p, off);
        if (lane == 0) out[n] = p + lp_b[0];
    } else {
        int c = 2 * lane;
        float2 bv = *(const float2*)(bias + c);
        float v0 = acc_lo * inv + bv.x;
        float v1 = acc_hi * inv + bv.y;
        v0 = v0 >= 0.f ? v0 : pa * v0;
        v1 = v1 >= 0.f ? v1 : pa * v1;
        nt_store2(out + (size_t)n * 128 + c, v0, v1);
    }
}

extern "C" void kernel_launch(void* const* d_in, const int* in_sizes, int n_in,
                              void* d_out, int out_size, void* d_ws, size_t ws_size,
                              hipStream_t stream) {
    const float* x   = (const float*)d_in[0];
    const int*   ei  = (const int*)d_in[1];
    const float* W1  = (const float*)d_in[2];
    const float* as1 = (const float*)d_in[3];
    const float* ad1 = (const float*)d_in[4];
    const float* b1  = (const float*)d_in[5];
    const float* W2  = (const float*)d_in[6];
    const float* as2 = (const float*)d_in[7];
    const float* ad2 = (const float*)d_in[8];
    const float* b2  = (const float*)d_in[9];
    const float* W3  = (const float*)d_in[10];
    const float* as3 = (const float*)d_in[11];
    const float* ad3 = (const float*)d_in[12];
    const float* b3  = (const float*)d_in[13];
    const float* lpw = (const float*)d_in[14];
    const float* lpb = (const float*)d_in[15];
    const float* pa  = (const float*)d_in[16];
    float* out = (float*)d_out;

    char* ws = (char*)d_ws;
    size_t off = 0;
    auto alloc = [&](size_t bytes) {
        void* p = ws + off;
        off = (off + bytes + 255) & ~(size_t)255;
        return p;
    };
    int*   rowptr = (int*)alloc((NN + 1) * sizeof(int));
    int*   cursor = (int*)alloc((NN + 1) * sizeof(int));
    int*   counts = (int*)alloc((size_t)NN * sizeof(int));
    int*   bsums  = (int*)alloc(64 * sizeof(int));
    int*   bex    = (int*)alloc(64 * sizeof(int));
    int*   csr    = (int*)alloc((size_t)TE * sizeof(int));
    float* al     = (float*)alloc((size_t)NN * 4 * sizeof(float));
    float* xs     = (float*)alloc((size_t)NN * 128 * sizeof(float));
    float* h      = (float*)alloc((size_t)NN * 128 * sizeof(float));
    (void)ws_size; (void)n_in; (void)in_sizes; (void)out_size;

    const int NB = (NN + 1023) / 1024;       // 49
    const int GEMM_GRID = (NN + 63) / 64;    // 782
    const int AGG_GRID  = (NN + 3) / 4;      // 12500

    (void)hipMemsetAsync(counts, 0, (size_t)NN * sizeof(int), stream);
    k_count<<<(TE + 255) / 256, 256, 0, stream>>>(ei, counts);
    k_bsum<<<NB, 1024, 0, stream>>>(counts, bsums);
    k_bscan<<<1, 64, 0, stream>>>(bsums, bex, NB);
    k_scan<<<NB, 1024, 0, stream>>>(counts, bex, rowptr, cursor);
    k_scatter<<<(TE + 255) / 256, 256, 0, stream>>>(ei, cursor, csr);

    k_gemm<<<GEMM_GRID, 256, 0, stream>>>(x, W1, as1, ad1, xs, al);
    k_agg<0><<<AGG_GRID, 256, 0, stream>>>(xs, al, rowptr, csr, b1, nullptr, nullptr, pa, h);
    k_gemm<<<GEMM_GRID, 256, 0, stream>>>(h, W2, as2, ad2, xs, al);
    k_agg<0><<<AGG_GRID, 256, 0, stream>>>(xs, al, rowptr, csr, b2, nullptr, nullptr, pa, h);
    k_gemm<<<GEMM_GRID, 256, 0, stream>>>(h, W3, as3, ad3, xs, al);
    k_agg<1><<<AGG_GRID, 256, 0, stream>>>(xs, al, rowptr, csr, b3, lpw, lpb, pa, out);
}

// Round 19
// 323.854 us; speedup vs baseline: 7.4297x; 1.1899x over previous
//
#include <hip/hip_runtime.h>

#define NN 50000
#define NE 800000
#define TE (NE + NN)

__device__ __forceinline__ float lrelu02(float x) { return x >= 0.f ? x : 0.2f * x; }

typedef const __attribute__((address_space(1))) unsigned int* gas_ptr;
typedef __attribute__((address_space(3))) unsigned int* las_ptr;
typedef _Float16 vh4 __attribute__((ext_vector_type(4)));
typedef _Float16 vh2 __attribute__((ext_vector_type(2)));
typedef unsigned int vu2 __attribute__((ext_vector_type(2)));
typedef float vf2 __attribute__((ext_vector_type(2)));

__device__ __forceinline__ void dma16(const float* g, float* l) {
    __builtin_amdgcn_global_load_lds((gas_ptr)g, (las_ptr)l, 16, 0, 0);
}

__global__ void k_count(const int* __restrict__ ei, int* __restrict__ counts) {
    int e = blockIdx.x * blockDim.x + threadIdx.x;
    if (e >= TE) return;
    int dst = (e < NE) ? ei[NE + e] : (e - NE);
    atomicAdd(&counts[dst], 1);
}

__global__ void k_bsum(const int* __restrict__ counts, int* __restrict__ bsums) {
    __shared__ int sm[1024];
    int i = blockIdx.x * 1024 + threadIdx.x;
    sm[threadIdx.x] = (i < NN) ? counts[i] : 0;
    __syncthreads();
    for (int off = 512; off > 0; off >>= 1) {
        if ((int)threadIdx.x < off) sm[threadIdx.x] += sm[threadIdx.x + off];
        __syncthreads();
    }
    if (threadIdx.x == 0) bsums[blockIdx.x] = sm[0];
}

__global__ void k_bscan(const int* __restrict__ bsums, int* __restrict__ bex, int nb) {
    int l = threadIdx.x;
    int v = (l < nb) ? bsums[l] : 0;
    int orig = v;
    for (int d = 1; d < 64; d <<= 1) {
        int t = __shfl_up(v, d);
        if (l >= d) v += t;
    }
    if (l <= nb) bex[l] = v - orig;
}

__global__ void k_scan(const int* __restrict__ counts, const int* __restrict__ bex,
                       int* __restrict__ rowptr, int* __restrict__ cursor) {
    __shared__ int sm[1024];
    int t = threadIdx.x;
    int i = blockIdx.x * 1024 + t;
    int c = (i < NN) ? counts[i] : 0;
    sm[t] = c;
    __syncthreads();
    for (int off = 1; off < 1024; off <<= 1) {
        int v = (t >= off) ? sm[t - off] : 0;
        __syncthreads();
        sm[t] += v;
        __syncthreads();
    }
    int ex = bex[blockIdx.x] + sm[t] - c;
    if (i <= NN) rowptr[i] = ex;
    if (i < NN) cursor[i] = ex;
}

__global__ void k_scatter(const int* __restrict__ ei, int* __restrict__ cursor, int* __restrict__ csr) {
    int e = blockIdx.x * blockDim.x + threadIdx.x;
    if (e >= TE) return;
    int src, dst;
    if (e < NE) { src = ei[e]; dst = ei[NE + e]; }
    else { src = e - NE; dst = src; }
    int pos = atomicAdd(&cursor[dst], 1);
    csr[pos] = src;
}

// GEMM X[N,128] @ W[128,128] -> XS[N,128] (FP16!) + AL logits (fp32).
// Round-13 structure; XS stored as fp16 (only the agg gather reads XS ->
// halves agg's compulsory per-XCD L2-fill traffic). NT 8-byte stores.
__global__ __launch_bounds__(256) void k_gemm(const float* __restrict__ X, const float* __restrict__ W,
                                              const float* __restrict__ as_, const float* __restrict__ ad_,
                                              _Float16* __restrict__ XS, float* __restrict__ AL) {
    __shared__ float sX[64 * 128];   // 32 KB
    int t = threadIdx.x;
    int lane = t & 63;
    int wv = __builtin_amdgcn_readfirstlane(t >> 6);
    int tc = t & 31;
    int tr = t >> 5;
    size_t chunk = (size_t)blockIdx.x * 64;
    size_t base = chunk * 128;
    const size_t gmax = (size_t)NN * 128 - 4;
#pragma unroll
    for (int i = 0; i < 8; i++) {
        size_t off = ((size_t)(wv * 8 + i)) * 256 + (size_t)lane * 4;
        size_t g = base + off;
        if (g > gmax) g = gmax;
        dma16(X + g, &sX[off]);
    }
    __syncthreads();
    float4 av = *(const float4*)(as_ + tc * 4);
    float4 dv = *(const float4*)(ad_ + tc * 4);
    float acc[8][4];
#pragma unroll
    for (int i = 0; i < 8; i++)
#pragma unroll
        for (int j = 0; j < 4; j++) acc[i][j] = 0.f;
#pragma unroll 2
    for (int kk = 0; kk < 128; kk += 4) {
        float4 wq[4];
#pragma unroll
        for (int k = 0; k < 4; k++)
            wq[k] = *(const float4*)(W + (size_t)(kk + k) * 128 + tc * 4);
#pragma unroll
        for (int i = 0; i < 8; i++) {
            float4 xv = *(const float4*)(&sX[(tr * 8 + i) * 128 + kk]);
            acc[i][0] = fmaf(xv.x, wq[0].x, acc[i][0]);
            acc[i][1] = fmaf(xv.x, wq[0].y, acc[i][1]);
            acc[i][2] = fmaf(xv.x, wq[0].z, acc[i][2]);
            acc[i][3] = fmaf(xv.x, wq[0].w, acc[i][3]);
            acc[i][0] = fmaf(xv.y, wq[1].x, acc[i][0]);
            acc[i][1] = fmaf(xv.y, wq[1].y, acc[i][1]);
            acc[i][2] = fmaf(xv.y, wq[1].z, acc[i][2]);
            acc[i][3] = fmaf(xv.y, wq[1].w, acc[i][3]);
            acc[i][0] = fmaf(xv.z, wq[2].x, acc[i][0]);
            acc[i][1] = fmaf(xv.z, wq[2].y, acc[i][1]);
            acc[i][2] = fmaf(xv.z, wq[2].z, acc[i][2]);
            acc[i][3] = fmaf(xv.z, wq[2].w, acc[i][3]);
            acc[i][0] = fmaf(xv.w, wq[3].x, acc[i][0]);
            acc[i][1] = fmaf(xv.w, wq[3].y, acc[i][1]);
            acc[i][2] = fmaf(xv.w, wq[3].z, acc[i][2]);
            acc[i][3] = fmaf(xv.w, wq[3].w, acc[i][3]);
        }
    }
#pragma unroll
    for (int i = 0; i < 8; i++) {
        size_t row = chunk + tr * 8 + i;
        bool ok = row < NN;
        if (ok) {
            vh4 hv;
            hv.x = (_Float16)acc[i][0];
            hv.y = (_Float16)acc[i][1];
            hv.z = (_Float16)acc[i][2];
            hv.w = (_Float16)acc[i][3];
            vu2 u = __builtin_bit_cast(vu2, hv);
            __builtin_nontemporal_store(u, (vu2*)(XS + row * 128 + tc * 4));
        }
        float s = acc[i][0] * av.x + acc[i][1] * av.y + acc[i][2] * av.z + acc[i][3] * av.w;
        float dd = acc[i][0] * dv.x + acc[i][1] * dv.y + acc[i][2] * dv.z + acc[i][3] * dv.w;
#pragma unroll
        for (int off = 8; off > 0; off >>= 1) {
            s += __shfl_xor(s, off);
            dd += __shfl_xor(dd, off);
        }
        if (ok && (tc & 15) == 0) {
            int h = tc >> 4;
            AL[row * 4 + h] = s;
            AL[row * 4 + 2 + h] = dd;
        }
    }
}

// Aggregation: round-4/7 structure, gather operand now FP16 (4 B/lane,
// 256 B/row coalesced) -> compulsory per-XCD fill halves to ~103 MB.
// All accumulation fp32; alpha weights from fp32 AL. NT h stores.
template <int LAST>
__global__ __launch_bounds__(256) void k_agg(const _Float16* __restrict__ XS, const float* __restrict__ AL,
                                             const int* __restrict__ rowptr, const int* __restrict__ csr,
                                             const float* __restrict__ bias, const float* __restrict__ lp_w,
                                             const float* __restrict__ lp_b, const float* __restrict__ prelu_a,
                                             float* __restrict__ out) {
    int wv = threadIdx.x >> 6, lane = threadIdx.x & 63;
    int n = blockIdx.x * 4 + wv;
    if (n >= NN) return;
    int beg = rowptr[n], end = rowptr[n + 1];
    float2 aldv = *(const float2*)(AL + (size_t)n * 4 + 2);
    float ald0 = aldv.x, ald1 = aldv.y;
    float acc_lo = 0.f, acc_hi = 0.f, den0 = 0.f, den1 = 0.f;
    for (int base = beg; base < end; base += 64) {
        int i = base + lane;
        float w0 = 0.f, w1 = 0.f;
        int sv = 0;
        if (i < end) {
            sv = csr[i];
            float2 av = *(const float2*)(AL + (size_t)sv * 4);
            w0 = __expf(lrelu02(av.x + ald0));
            w1 = __expf(lrelu02(av.y + ald1));
        }
        den0 += w0;
        den1 += w1;
        int cnt = min(64, end - base);
        int j = 0;
        for (; j + 8 <= cnt; j += 8) {
            int s[8];
            float ww[8];
#pragma unroll
            for (int jj = 0; jj < 8; jj++) {
                s[jj] = __shfl(sv, j + jj);
                float q0 = __shfl(w0, j + jj), q1 = __shfl(w1, j + jj);
                ww[jj] = (lane < 32) ? q0 : q1;
            }
            vh2 xv[8];
#pragma unroll
            for (int jj = 0; jj < 8; jj++)
                xv[jj] = *(const vh2*)(XS + (size_t)s[jj] * 128 + 2 * lane);
#pragma unroll
            for (int jj = 0; jj < 8; jj++) {
                acc_lo = fmaf(ww[jj], (float)xv[jj].x, acc_lo);
                acc_hi = fmaf(ww[jj], (float)xv[jj].y, acc_hi);
            }
        }
        for (; j < cnt; j++) {
            int s = __shfl(sv, j);
            float q0 = __shfl(w0, j), q1 = __shfl(w1, j);
            float w = (lane < 32) ? q0 : q1;
            vh2 xv = *(const vh2*)(XS + (size_t)s * 128 + 2 * lane);
            acc_lo = fmaf(w, (float)xv.x, acc_lo);
            acc_hi = fmaf(w, (float)xv.y, acc_hi);
        }
    }
#pragma unroll
    for (int off = 32; off > 0; off >>= 1) {
        den0 += __shfl_xor(den0, off);
        den1 += __shfl_xor(den1, off);
    }
    float pa = prelu_a[0];
    float densel = (lane < 32) ? den0 : den1;
    float inv = 1.f / (densel + 1e-16f);
    if (LAST) {
        float hlo = acc_lo * inv, hhi = acc_hi * inv;
        float olo = __shfl_xor(hlo, 32), ohi = __shfl_xor(hhi, 32);
        float p = 0.f;
        if (lane < 32) {
            int c = 2 * lane;
            float v0 = 0.5f * (hlo + olo) + bias[c];
            float v1 = 0.5f * (hhi + ohi) + bias[c + 1];
            v0 = v0 >= 0.f ? v0 : pa * v0;
            v1 = v1 >= 0.f ? v1 : pa * v1;
            p = v0 * lp_w[c] + v1 * lp_w[c + 1];
        }
#pragma unroll
        for (int off = 32; off > 0; off >>= 1) p += __shfl_xor(p, off);
        if (lane == 0) out[n] = p + lp_b[0];
    } else {
        int c = 2 * lane;
        float2 bv = *(const float2*)(bias + c);
        float v0 = acc_lo * inv + bv.x;
        float v1 = acc_hi * inv + bv.y;
        v0 = v0 >= 0.f ? v0 : pa * v0;
        v1 = v1 >= 0.f ? v1 : pa * v1;
        vf2 o; o.x = v0; o.y = v1;
        __builtin_nontemporal_store(o, (vf2*)(out + (size_t)n * 128 + c));
    }
}

extern "C" void kernel_launch(void* const* d_in, const int* in_sizes, int n_in,
                              void* d_out, int out_size, void* d_ws, size_t ws_size,
                              hipStream_t stream) {
    const float* x   = (const float*)d_in[0];
    const int*   ei  = (const int*)d_in[1];
    const float* W1  = (const float*)d_in[2];
    const float* as1 = (const float*)d_in[3];
    const float* ad1 = (const float*)d_in[4];
    const float* b1  = (const float*)d_in[5];
    const float* W2  = (const float*)d_in[6];
    const float* as2 = (const float*)d_in[7];
    const float* ad2 = (const float*)d_in[8];
    const float* b2  = (const float*)d_in[9];
    const float* W3  = (const float*)d_in[10];
    const float* as3 = (const float*)d_in[11];
    const float* ad3 = (const float*)d_in[12];
    const float* b3  = (const float*)d_in[13];
    const float* lpw = (const float*)d_in[14];
    const float* lpb = (const float*)d_in[15];
    const float* pa  = (const float*)d_in[16];
    float* out = (float*)d_out;

    char* ws = (char*)d_ws;
    size_t off = 0;
    auto alloc = [&](size_t bytes) {
        void* p = ws + off;
        off = (off + bytes + 255) & ~(size_t)255;
        return p;
    };
    int*      rowptr = (int*)alloc((NN + 1) * sizeof(int));
    int*      cursor = (int*)alloc((NN + 1) * sizeof(int));
    int*      counts = (int*)alloc((size_t)NN * sizeof(int));
    int*      bsums  = (int*)alloc(64 * sizeof(int));
    int*      bex    = (int*)alloc(64 * sizeof(int));
    int*      csr    = (int*)alloc((size_t)TE * sizeof(int));
    float*    al     = (float*)alloc((size_t)NN * 4 * sizeof(float));
    _Float16* xs     = (_Float16*)alloc((size_t)NN * 128 * sizeof(_Float16));
    float*    h      = (float*)alloc((size_t)NN * 128 * sizeof(float));
    (void)ws_size; (void)n_in; (void)in_sizes; (void)out_size;

    const int NB = (NN + 1023) / 1024;       // 49
    const int GEMM_GRID = (NN + 63) / 64;    // 782
    const int AGG_GRID  = (NN + 3) / 4;      // 12500

    (void)hipMemsetAsync(counts, 0, (size_t)NN * sizeof(int), stream);
    k_count<<<(TE + 255) / 256, 256, 0, stream>>>(ei, counts);
    k_bsum<<<NB, 1024, 0, stream>>>(counts, bsums);
    k_bscan<<<1, 64, 0, stream>>>(bsums, bex, NB);
    k_scan<<<NB, 1024, 0, stream>>>(counts, bex, rowptr, cursor);
    k_scatter<<<(TE + 255) / 256, 256, 0, stream>>>(ei, cursor, csr);

    k_gemm<<<GEMM_GRID, 256, 0, stream>>>(x, W1, as1, ad1, xs, al);
    k_agg<0><<<AGG_GRID, 256, 0, stream>>>(xs, al, rowptr, csr, b1, nullptr, nullptr, pa, h);
    k_gemm<<<GEMM_GRID, 256, 0, stream>>>(h, W2, as2, ad2, xs, al);
    k_agg<0><<<AGG_GRID, 256, 0, stream>>>(xs, al, rowptr, csr, b2, nullptr, nullptr, pa, h);
    k_gemm<<<GEMM_GRID, 256, 0, stream>>>(h, W3, as3, ad3, xs, al);
    k_agg<1><<<AGG_GRID, 256, 0, stream>>>(xs, al, rowptr, csr, b3, lpw, lpb, pa, out);
}

// Round 20
// 309.271 us; speedup vs baseline: 7.7800x; 1.0472x over previous
//
#include <hip/hip_runtime.h>

#define NN 50000
#define NE 800000
#define TE (NE + NN)
#define NRANGE 8
#define RSPAN ((NN + NRANGE - 1) / NRANGE)   // 6250

__device__ __forceinline__ float lrelu02(float x) { return x >= 0.f ? x : 0.2f * x; }

typedef const __attribute__((address_space(1))) unsigned int* gas_ptr;
typedef __attribute__((address_space(3))) unsigned int* las_ptr;
typedef _Float16 vh4 __attribute__((ext_vector_type(4)));
typedef _Float16 vh2 __attribute__((ext_vector_type(2)));
typedef unsigned int vu2 __attribute__((ext_vector_type(2)));
typedef float vf2 __attribute__((ext_vector_type(2)));

__device__ __forceinline__ void dma16(const float* g, float* l) {
    __builtin_amdgcn_global_load_lds((gas_ptr)g, (las_ptr)l, 16, 0, 0);
}

// Count: 8x blocks; block (chunk, r=blockIdx&7) handles only dst-range r ->
// counts lines for range r are touched by one XCD only (round-robin dispatch).
__global__ void k_count(const int* __restrict__ ei, int* __restrict__ counts) {
    int r = blockIdx.x & 7;
    int e = (blockIdx.x >> 3) * 256 + threadIdx.x;
    if (e >= TE) return;
    int dst = (e < NE) ? ei[NE + e] : (e - NE);
    if (dst >= r * RSPAN && dst < (r + 1) * RSPAN)
        atomicAdd(&counts[dst], 1);
}

__global__ void k_bsum(const int* __restrict__ counts, int* __restrict__ bsums) {
    __shared__ int sm[1024];
    int i = blockIdx.x * 1024 + threadIdx.x;
    sm[threadIdx.x] = (i < NN) ? counts[i] : 0;
    __syncthreads();
    for (int off = 512; off > 0; off >>= 1) {
        if ((int)threadIdx.x < off) sm[threadIdx.x] += sm[threadIdx.x + off];
        __syncthreads();
    }
    if (threadIdx.x == 0) bsums[blockIdx.x] = sm[0];
}

__global__ void k_bscan(const int* __restrict__ bsums, int* __restrict__ bex, int nb) {
    int l = threadIdx.x;
    int v = (l < nb) ? bsums[l] : 0;
    int orig = v;
    for (int d = 1; d < 64; d <<= 1) {
        int t = __shfl_up(v, d);
        if (l >= d) v += t;
    }
    if (l <= nb) bex[l] = v - orig;
}

__global__ void k_scan(const int* __restrict__ counts, const int* __restrict__ bex,
                       int* __restrict__ rowptr, int* __restrict__ cursor) {
    __shared__ int sm[1024];
    int t = threadIdx.x;
    int i = blockIdx.x * 1024 + t;
    int c = (i < NN) ? counts[i] : 0;
    sm[t] = c;
    __syncthreads();
    for (int off = 1; off < 1024; off <<= 1) {
        int v = (t >= off) ? sm[t - off] : 0;
        __syncthreads();
        sm[t] += v;
        __syncthreads();
    }
    int ex = bex[blockIdx.x] + sm[t] - c;
    if (i <= NN) rowptr[i] = ex;
    if (i < NN) cursor[i] = ex;
}

// Scatter: same 8x dst-range split. All csr lines of range r are written from
// one XCD -> coalesce in its L2 (write amplification 54MB -> ~3.4MB). The 8x
// re-read of the dst array is L3-absorbed (consecutive blocks, same chunk).
__global__ void k_scatter(const int* __restrict__ ei, int* __restrict__ cursor, int* __restrict__ csr) {
    int r = blockIdx.x & 7;
    int e = (blockIdx.x >> 3) * 256 + threadIdx.x;
    if (e >= TE) return;
    int dst = (e < NE) ? ei[NE + e] : (e - NE);
    if (dst >= r * RSPAN && dst < (r + 1) * RSPAN) {
        int src = (e < NE) ? ei[e] : dst;
        int pos = atomicAdd(&cursor[dst], 1);
        csr[pos] = src;
    }
}

// GEMM X[N,128] @ W[128,128] -> XS[N,128] (FP16) + AL logits (fp32).
// Round-13 structure; XS stored fp16 NT (halves agg's compulsory fill).
__global__ __launch_bounds__(256) void k_gemm(const float* __restrict__ X, const float* __restrict__ W,
                                              const float* __restrict__ as_, const float* __restrict__ ad_,
                                              _Float16* __restrict__ XS, float* __restrict__ AL) {
    __shared__ float sX[64 * 128];   // 32 KB
    int t = threadIdx.x;
    int lane = t & 63;
    int wv = __builtin_amdgcn_readfirstlane(t >> 6);
    int tc = t & 31;
    int tr = t >> 5;
    size_t chunk = (size_t)blockIdx.x * 64;
    size_t base = chunk * 128;
    const size_t gmax = (size_t)NN * 128 - 4;
#pragma unroll
    for (int i = 0; i < 8; i++) {
        size_t off = ((size_t)(wv * 8 + i)) * 256 + (size_t)lane * 4;
        size_t g = base + off;
        if (g > gmax) g = gmax;
        dma16(X + g, &sX[off]);
    }
    __syncthreads();
    float4 av = *(const float4*)(as_ + tc * 4);
    float4 dv = *(const float4*)(ad_ + tc * 4);
    float acc[8][4];
#pragma unroll
    for (int i = 0; i < 8; i++)
#pragma unroll
        for (int j = 0; j < 4; j++) acc[i][j] = 0.f;
#pragma unroll 2
    for (int kk = 0; kk < 128; kk += 4) {
        float4 wq[4];
#pragma unroll
        for (int k = 0; k < 4; k++)
            wq[k] = *(const float4*)(W + (size_t)(kk + k) * 128 + tc * 4);
#pragma unroll
        for (int i = 0; i < 8; i++) {
            float4 xv = *(const float4*)(&sX[(tr * 8 + i) * 128 + kk]);
            acc[i][0] = fmaf(xv.x, wq[0].x, acc[i][0]);
            acc[i][1] = fmaf(xv.x, wq[0].y, acc[i][1]);
            acc[i][2] = fmaf(xv.x, wq[0].z, acc[i][2]);
            acc[i][3] = fmaf(xv.x, wq[0].w, acc[i][3]);
            acc[i][0] = fmaf(xv.y, wq[1].x, acc[i][0]);
            acc[i][1] = fmaf(xv.y, wq[1].y, acc[i][1]);
            acc[i][2] = fmaf(xv.y, wq[1].z, acc[i][2]);
            acc[i][3] = fmaf(xv.y, wq[1].w, acc[i][3]);
            acc[i][0] = fmaf(xv.z, wq[2].x, acc[i][0]);
            acc[i][1] = fmaf(xv.z, wq[2].y, acc[i][1]);
            acc[i][2] = fmaf(xv.z, wq[2].z, acc[i][2]);
            acc[i][3] = fmaf(xv.z, wq[2].w, acc[i][3]);
            acc[i][0] = fmaf(xv.w, wq[3].x, acc[i][0]);
            acc[i][1] = fmaf(xv.w, wq[3].y, acc[i][1]);
            acc[i][2] = fmaf(xv.w, wq[3].z, acc[i][2]);
            acc[i][3] = fmaf(xv.w, wq[3].w, acc[i][3]);
        }
    }
#pragma unroll
    for (int i = 0; i < 8; i++) {
        size_t row = chunk + tr * 8 + i;
        bool ok = row < NN;
        if (ok) {
            vh4 hv;
            hv.x = (_Float16)acc[i][0];
            hv.y = (_Float16)acc[i][1];
            hv.z = (_Float16)acc[i][2];
            hv.w = (_Float16)acc[i][3];
            vu2 u = __builtin_bit_cast(vu2, hv);
            __builtin_nontemporal_store(u, (vu2*)(XS + row * 128 + tc * 4));
        }
        float s = acc[i][0] * av.x + acc[i][1] * av.y + acc[i][2] * av.z + acc[i][3] * av.w;
        float dd = acc[i][0] * dv.x + acc[i][1] * dv.y + acc[i][2] * dv.z + acc[i][3] * dv.w;
#pragma unroll
        for (int off = 8; off > 0; off >>= 1) {
            s += __shfl_xor(s, off);
            dd += __shfl_xor(dd, off);
        }
        if (ok && (tc & 15) == 0) {
            int h = tc >> 4;
            AL[row * 4 + h] = s;
            AL[row * 4 + 2 + h] = dd;
        }
    }
}

// Aggregation: round-4/7 structure, FP16 gather operand (4 B/lane, 256 B/row).
// fp32 accumulation; NT h stores.
template <int LAST>
__global__ __launch_bounds__(256) void k_agg(const _Float16* __restrict__ XS, const float* __restrict__ AL,
                                             const int* __restrict__ rowptr, const int* __restrict__ csr,
                                             const float* __restrict__ bias, const float* __restrict__ lp_w,
                                             const float* __restrict__ lp_b, const float* __restrict__ prelu_a,
                                             float* __restrict__ out) {
    int wv = threadIdx.x >> 6, lane = threadIdx.x & 63;
    int n = blockIdx.x * 4 + wv;
    if (n >= NN) return;
    int beg = rowptr[n], end = rowptr[n + 1];
    float2 aldv = *(const float2*)(AL + (size_t)n * 4 + 2);
    float ald0 = aldv.x, ald1 = aldv.y;
    float acc_lo = 0.f, acc_hi = 0.f, den0 = 0.f, den1 = 0.f;
    for (int base = beg; base < end; base += 64) {
        int i = base + lane;
        float w0 = 0.f, w1 = 0.f;
        int sv = 0;
        if (i < end) {
            sv = csr[i];
            float2 av = *(const float2*)(AL + (size_t)sv * 4);
            w0 = __expf(lrelu02(av.x + ald0));
            w1 = __expf(lrelu02(av.y + ald1));
        }
        den0 += w0;
        den1 += w1;
        int cnt = min(64, end - base);
        int j = 0;
        for (; j + 8 <= cnt; j += 8) {
            int s[8];
            float ww[8];
#pragma unroll
            for (int jj = 0; jj < 8; jj++) {
                s[jj] = __shfl(sv, j + jj);
                float q0 = __shfl(w0, j + jj), q1 = __shfl(w1, j + jj);
                ww[jj] = (lane < 32) ? q0 : q1;
            }
            vh2 xv[8];
#pragma unroll
            for (int jj = 0; jj < 8; jj++)
                xv[jj] = *(const vh2*)(XS + (size_t)s[jj] * 128 + 2 * lane);
#pragma unroll
            for (int jj = 0; jj < 8; jj++) {
                acc_lo = fmaf(ww[jj], (float)xv[jj].x, acc_lo);
                acc_hi = fmaf(ww[jj], (float)xv[jj].y, acc_hi);
            }
        }
        for (; j < cnt; j++) {
            int s = __shfl(sv, j);
            float q0 = __shfl(w0, j), q1 = __shfl(w1, j);
            float w = (lane < 32) ? q0 : q1;
            vh2 xv = *(const vh2*)(XS + (size_t)s * 128 + 2 * lane);
            acc_lo = fmaf(w, (float)xv.x, acc_lo);
            acc_hi = fmaf(w, (float)xv.y, acc_hi);
        }
    }
#pragma unroll
    for (int off = 32; off > 0; off >>= 1) {
        den0 += __shfl_xor(den0, off);
        den1 += __shfl_xor(den1, off);
    }
    float pa = prelu_a[0];
    float densel = (lane < 32) ? den0 : den1;
    float inv = 1.f / (densel + 1e-16f);
    if (LAST) {
        float hlo = acc_lo * inv, hhi = acc_hi * inv;
        float olo = __shfl_xor(hlo, 32), ohi = __shfl_xor(hhi, 32);
        float p = 0.f;
        if (lane < 32) {
            int c = 2 * lane;
            float v0 = 0.5f * (hlo + olo) + bias[c];
            float v1 = 0.5f * (hhi + ohi) + bias[c + 1];
            v0 = v0 >= 0.f ? v0 : pa * v0;
            v1 = v1 >= 0.f ? v1 : pa * v1;
            p = v0 * lp_w[c] + v1 * lp_w[c + 1];
        }
#pragma unroll
        for (int off = 32; off > 0; off >>= 1) p += __shfl_xor(p, off);
        if (lane == 0) out[n] = p + lp_b[0];
    } else {
        int c = 2 * lane;
        float2 bv = *(const float2*)(bias + c);
        float v0 = acc_lo * inv + bv.x;
        float v1 = acc_hi * inv + bv.y;
        v0 = v0 >= 0.f ? v0 : pa * v0;
        v1 = v1 >= 0.f ? v1 : pa * v1;
        vf2 o; o.x = v0; o.y = v1;
        __builtin_nontemporal_store(o, (vf2*)(out + (size_t)n * 128 + c));
    }
}

extern "C" void kernel_launch(void* const* d_in, const int* in_sizes, int n_in,
                              void* d_out, int out_size, void* d_ws, size_t ws_size,
                              hipStream_t stream) {
    const float* x   = (const float*)d_in[0];
    const int*   ei  = (const int*)d_in[1];
    const float* W1  = (const float*)d_in[2];
    const float* as1 = (const float*)d_in[3];
    const float* ad1 = (const float*)d_in[4];
    const float* b1  = (const float*)d_in[5];
    const float* W2  = (const float*)d_in[6];
    const float* as2 = (const float*)d_in[7];
    const float* ad2 = (const float*)d_in[8];
    const float* b2  = (const float*)d_in[9];
    const float* W3  = (const float*)d_in[10];
    const float* as3 = (const float*)d_in[11];
    const float* ad3 = (const float*)d_in[12];
    const float* b3  = (const float*)d_in[13];
    const float* lpw = (const float*)d_in[14];
    const float* lpb = (const float*)d_in[15];
    const float* pa  = (const float*)d_in[16];
    float* out = (float*)d_out;

    char* ws = (char*)d_ws;
    size_t off = 0;
    auto alloc = [&](size_t bytes) {
        void* p = ws + off;
        off = (off + bytes + 255) & ~(size_t)255;
        return p;
    };
    int*      rowptr = (int*)alloc((NN + 1) * sizeof(int));
    int*      cursor = (int*)alloc((NN + 1) * sizeof(int));
    int*      counts = (int*)alloc((size_t)NN * sizeof(int));
    int*      bsums  = (int*)alloc(64 * sizeof(int));
    int*      bex    = (int*)alloc(64 * sizeof(int));
    int*      csr    = (int*)alloc((size_t)TE * sizeof(int));
    float*    al     = (float*)alloc((size_t)NN * 4 * sizeof(float));
    _Float16* xs     = (_Float16*)alloc((size_t)NN * 128 * sizeof(_Float16));
    float*    h      = (float*)alloc((size_t)NN * 128 * sizeof(float));
    (void)ws_size; (void)n_in; (void)in_sizes; (void)out_size;

    const int NB = (NN + 1023) / 1024;       // 49
    const int GEMM_GRID = (NN + 63) / 64;    // 782
    const int AGG_GRID  = (NN + 3) / 4;      // 12500
    const int EDGE_GRID = 8 * ((TE + 255) / 256);   // 8x range-split

    (void)hipMemsetAsync(counts, 0, (size_t)NN * sizeof(int), stream);
    k_count<<<EDGE_GRID, 256, 0, stream>>>(ei, counts);
    k_bsum<<<NB, 1024, 0, stream>>>(counts, bsums);
    k_bscan<<<1, 64, 0, stream>>>(bsums, bex, NB);
    k_scan<<<NB, 1024, 0, stream>>>(counts, bex, rowptr, cursor);
    k_scatter<<<EDGE_GRID, 256, 0, stream>>>(ei, cursor, csr);

    k_gemm<<<GEMM_GRID, 256, 0, stream>>>(x, W1, as1, ad1, xs, al);
    k_agg<0><<<AGG_GRID, 256, 0, stream>>>(xs, al, rowptr, csr, b1, nullptr, nullptr, pa, h);
    k_gemm<<<GEMM_GRID, 256, 0, stream>>>(h, W2, as2, ad2, xs, al);
    k_agg<0><<<AGG_GRID, 256, 0, stream>>>(xs, al, rowptr, csr, b2, nullptr, nullptr, pa, h);
    k_gemm<<<GEMM_GRID, 256, 0, stream>>>(h, W3, as3, ad3, xs, al);
    k_agg<1><<<AGG_GRID, 256, 0, stream>>>(xs, al, rowptr, csr, b3, lpw, lpb, pa, out);
}